// Round 1
// baseline (488.434 us; speedup 1.0000x reference)
//
#include <hip/hip_runtime.h>
#include <hip/hip_bf16.h>
#include <math.h>

// Problem constants
#define B_ 4
#define T_ 2048
#define E_ 1024
#define H_ 16
#define DH_ 64

typedef __bf16 bf16x8 __attribute__((ext_vector_type(8)));
typedef __bf16 bf16x4 __attribute__((ext_vector_type(4)));
typedef float f32x4 __attribute__((ext_vector_type(4)));

// ---------------------------------------------------------------- casts
__global__ void cast_f32_to_bf16(const float* __restrict__ src,
                                 __bf16* __restrict__ dst, int n) {
    int i = (blockIdx.x * blockDim.x + threadIdx.x) * 4;
    if (i + 3 < n) {
        float4 f = *reinterpret_cast<const float4*>(src + i);
        bf16x4 o = { (__bf16)f.x, (__bf16)f.y, (__bf16)f.z, (__bf16)f.w };
        *reinterpret_cast<bf16x4*>(dst + i) = o;
    }
}

// in: [H][E][DH] f32  ->  out: [H][DH][E] bf16  (so GEMM B-frags read contiguous K)
__global__ void cast_transpose_w(const float* __restrict__ src,
                                 __bf16* __restrict__ dst) {
    int idx = blockIdx.x * blockDim.x + threadIdx.x;  // over H*DH*E = 1048576
    int e = idx & (E_ - 1);
    int d = (idx >> 10) & (DH_ - 1);
    int h = idx >> 16;
    dst[idx] = (__bf16)src[(h * E_ + e) * DH_ + d];
}

// ---------------------------------------------------------------- GEMM (C = A * Bt^T)
// A: [M][K] bf16 row-major;  Bt: [N][K] bf16 row-major;  C: [M][N]
// tile 128x64, BK=64, 256 threads (4 waves as 2x2), mfma_f32_16x16x32_bf16
#define BM 128
#define BN 64
#define BK 64

template<bool F32OUT>
__global__ __launch_bounds__(256) void gemm_bt(
    const __bf16* __restrict__ A, const __bf16* __restrict__ Bt,
    void* __restrict__ Cout, const float* __restrict__ bias,
    int K, int N, long sA, long sB, long sC, int Hmod) {

    __shared__ __bf16 As[BM][BK];
    __shared__ __bf16 Bs[BN][BK];

    int tid = threadIdx.x;
    int lane = tid & 63, wid = tid >> 6;
    int wr = wid >> 1, wc = wid & 1;
    int rlo = lane & 15, rhi = lane >> 4;

    int z = blockIdx.z;
    int bz = z / Hmod, hz = z % Hmod;
    const __bf16* Ab = A + (long)bz * sA + (long)blockIdx.x * BM * K;
    const __bf16* Bb = Bt + (long)hz * sB + (long)blockIdx.y * BN * K;

    f32x4 acc[4][2] = {};

    for (int k0 = 0; k0 < K; k0 += BK) {
        // stage A tile (128x64), XOR chunk-swizzled (chunk = 8 bf16 = 16B)
        #pragma unroll
        for (int p = 0; p < 4; p++) {
            int r = (tid >> 3) + p * 32;
            int c8 = (tid & 7) * 8;
            bf16x8 vv = *reinterpret_cast<const bf16x8*>(Ab + (long)r * K + k0 + c8);
            int cs = (c8 >> 3) ^ (r & 7);
            *reinterpret_cast<bf16x8*>(&As[r][cs * 8]) = vv;
        }
        // stage B tile (64x64)
        #pragma unroll
        for (int p = 0; p < 2; p++) {
            int r = (tid >> 3) + p * 32;
            int c8 = (tid & 7) * 8;
            bf16x8 vv = *reinterpret_cast<const bf16x8*>(Bb + (long)r * K + k0 + c8);
            int cs = (c8 >> 3) ^ (r & 7);
            *reinterpret_cast<bf16x8*>(&Bs[r][cs * 8]) = vv;
        }
        __syncthreads();

        #pragma unroll
        for (int kk = 0; kk < BK; kk += 32) {
            int ck = (kk + 8 * rhi) >> 3;
            bf16x8 af[4], bfr[2];
            #pragma unroll
            for (int mi = 0; mi < 4; mi++) {
                int r = wr * 64 + mi * 16 + rlo;
                af[mi] = *reinterpret_cast<const bf16x8*>(&As[r][(ck ^ (r & 7)) * 8]);
            }
            #pragma unroll
            for (int ni = 0; ni < 2; ni++) {
                int r = wc * 32 + ni * 16 + rlo;
                bfr[ni] = *reinterpret_cast<const bf16x8*>(&Bs[r][(ck ^ (r & 7)) * 8]);
            }
            #pragma unroll
            for (int mi = 0; mi < 4; mi++)
                #pragma unroll
                for (int ni = 0; ni < 2; ni++)
                    acc[mi][ni] = __builtin_amdgcn_mfma_f32_16x16x32_bf16(
                        af[mi], bfr[ni], acc[mi][ni], 0, 0, 0);
        }
        __syncthreads();
    }

    // epilogue: C row = 4*rhi + reg, col = rlo (verified gfx950 C/D layout)
    long rowbase = (long)blockIdx.x * BM + wr * 64;
    int colbase = blockIdx.y * BN + wc * 32;
    #pragma unroll
    for (int mi = 0; mi < 4; mi++) {
        #pragma unroll
        for (int ni = 0; ni < 2; ni++) {
            int cn = colbase + ni * 16 + rlo;
            #pragma unroll
            for (int r = 0; r < 4; r++) {
                long rm = rowbase + mi * 16 + rhi * 4 + r;
                if constexpr (F32OUT) {
                    float* C = (float*)Cout + (long)z * sC;
                    C[rm * N + cn] = acc[mi][ni][r] + bias[cn];
                } else {
                    __bf16* C = (__bf16*)Cout + (long)z * sC;
                    C[rm * N + cn] = (__bf16)acc[mi][ni][r];
                }
            }
        }
    }
}

// ---------------------------------------------------------------- attention
// grid (T/64, B*H); 256 threads = 4 waves; wave w owns q-rows [q0+16w, q0+16w+16)
__global__ __launch_bounds__(256) void attn_kernel(
    const __bf16* __restrict__ q, const __bf16* __restrict__ k,
    const __bf16* __restrict__ v, __bf16* __restrict__ attout) {

    __shared__ __bf16 Vt[DH_][64];      // V^T tile, chunk-swizzled
    __shared__ __bf16 Pl[4][16][64];    // per-wave P tile, chunk-swizzled

    int tid = threadIdx.x, lane = tid & 63, wid = tid >> 6;
    int rlo = lane & 15, rhi = lane >> 4;
    int q0 = blockIdx.x * 64;
    int bh = blockIdx.y;
    int b = bh >> 4, h = bh & 15;
    const __bf16* qb = q + (long)bh * T_ * DH_;
    const __bf16* kb = k + (long)bh * T_ * DH_;
    const __bf16* vb = v + (long)bh * T_ * DH_;

    // hoist Q fragments (2 d-ksteps)
    bf16x8 aq[2];
    {
        long qr = q0 + wid * 16 + rlo;
        aq[0] = *reinterpret_cast<const bf16x8*>(qb + qr * DH_ + 8 * rhi);
        aq[1] = *reinterpret_cast<const bf16x8*>(qb + qr * DH_ + 32 + 8 * rhi);
    }

    float m_[4], l_[4];
    f32x4 o[4] = {};
    #pragma unroll
    for (int r = 0; r < 4; r++) { m_[r] = -INFINITY; l_[r] = 0.f; }

    int ntiles = q0 / 64 + 1;
    for (int t = 0; t < ntiles; t++) {
        int kt0 = t * 64;
        // stage V^T (swizzled) cooperatively
        #pragma unroll
        for (int p = 0; p < 2; p++) {
            int kr = (tid >> 3) + p * 32;
            int d8 = (tid & 7) * 8;
            bf16x8 vv = *reinterpret_cast<const bf16x8*>(vb + (long)(kt0 + kr) * DH_ + d8);
            #pragma unroll
            for (int j = 0; j < 8; j++) {
                int d = d8 + j;
                Vt[d][(((kr >> 3) ^ (d & 7)) << 3) + (kr & 7)] = vv[j];
            }
        }
        __syncthreads();

        // S = (Q K^T) — K frags straight from global (L2-resident)
        f32x4 s[4];
        #pragma unroll
        for (int f = 0; f < 4; f++) {
            f32x4 accs = {};
            #pragma unroll
            for (int kk = 0; kk < 2; kk++) {
                bf16x8 bk = *reinterpret_cast<const bf16x8*>(
                    kb + (long)(kt0 + f * 16 + rlo) * DH_ + kk * 32 + 8 * rhi);
                accs = __builtin_amdgcn_mfma_f32_16x16x32_bf16(aq[kk], bk, accs, 0, 0, 0);
            }
            s[f] = accs;
        }

        // scale + causal mask (only the diagonal tile needs masking)
        bool diag = (kt0 == q0);
        #pragma unroll
        for (int f = 0; f < 4; f++) {
            int kcol = kt0 + f * 16 + rlo;
            #pragma unroll
            for (int r = 0; r < 4; r++) {
                float sv = s[f][r] * 0.125f;
                if (diag) {
                    int qrow = q0 + wid * 16 + rhi * 4 + r;
                    if (kcol > qrow) sv = -INFINITY;
                }
                s[f][r] = sv;
            }
        }

        // online softmax (row stats replicated across each 16-lane group)
        float so[4];
        #pragma unroll
        for (int r = 0; r < 4; r++) {
            float pm = fmaxf(fmaxf(s[0][r], s[1][r]), fmaxf(s[2][r], s[3][r]));
            pm = fmaxf(pm, __shfl_xor(pm, 1));
            pm = fmaxf(pm, __shfl_xor(pm, 2));
            pm = fmaxf(pm, __shfl_xor(pm, 4));
            pm = fmaxf(pm, __shfl_xor(pm, 8));
            float nm = fmaxf(m_[r], pm);
            so[r] = __expf(m_[r] - nm);
            float rsum = 0.f;
            #pragma unroll
            for (int f = 0; f < 4; f++) {
                float p = __expf(s[f][r] - nm);
                s[f][r] = p;
                rsum += p;
            }
            rsum += __shfl_xor(rsum, 1);
            rsum += __shfl_xor(rsum, 2);
            rsum += __shfl_xor(rsum, 4);
            rsum += __shfl_xor(rsum, 8);
            l_[r] = l_[r] * so[r] + rsum;
            m_[r] = nm;
        }
        #pragma unroll
        for (int fd = 0; fd < 4; fd++)
            #pragma unroll
            for (int r = 0; r < 4; r++)
                o[fd][r] *= so[r];

        // P -> bf16 -> per-wave LDS (swizzled)
        #pragma unroll
        for (int f = 0; f < 4; f++) {
            int col = f * 16 + rlo;
            #pragma unroll
            for (int r = 0; r < 4; r++) {
                int row = rhi * 4 + r;
                Pl[wid][row][(((col >> 3) ^ (row & 7)) << 3) + (col & 7)] = (__bf16)s[f][r];
            }
        }

        // O += P V
        #pragma unroll
        for (int kk = 0; kk < 2; kk++) {
            int ck = kk * 4 + rhi;
            bf16x8 ap = *reinterpret_cast<const bf16x8*>(&Pl[wid][rlo][(ck ^ (rlo & 7)) * 8]);
            #pragma unroll
            for (int fd = 0; fd < 4; fd++) {
                int vrow = fd * 16 + rlo;
                bf16x8 bv = *reinterpret_cast<const bf16x8*>(&Vt[vrow][(ck ^ (vrow & 7)) * 8]);
                o[fd] = __builtin_amdgcn_mfma_f32_16x16x32_bf16(ap, bv, o[fd], 0, 0, 0);
            }
        }
        __syncthreads();   // before next tile overwrites Vt
    }

    // normalize + write attout[b*T + qrow][h*64 + d]
    #pragma unroll
    for (int r = 0; r < 4; r++) {
        float inv = 1.f / l_[r];
        long qrow = q0 + wid * 16 + rhi * 4 + r;
        #pragma unroll
        for (int fd = 0; fd < 4; fd++) {
            int d = fd * 16 + rlo;
            attout[((long)b * T_ + qrow) * E_ + h * DH_ + d] = (__bf16)(o[fd][r] * inv);
        }
    }
}

// ---------------------------------------------------------------- launcher
extern "C" void kernel_launch(void* const* d_in, const int* in_sizes, int n_in,
                              void* d_out, int out_size, void* d_ws, size_t ws_size,
                              hipStream_t stream) {
    const float* x  = (const float*)d_in[0];
    const float* Wq = (const float*)d_in[1];
    const float* Wk = (const float*)d_in[2];
    const float* Wv = (const float*)d_in[3];
    const float* Wp = (const float*)d_in[4];
    const float* bp = (const float*)d_in[5];

    char* ws = (char*)d_ws;
    const long SZ_XE = (long)B_ * T_ * E_ * 2;      // 16 MB (bf16 [B*T][E])
    const long SZ_W  = (long)H_ * DH_ * E_ * 2;     // 2 MB
    __bf16* xb  = (__bf16*)(ws);                    // x bf16; REUSED as attout after QKV
    __bf16* qb  = (__bf16*)(ws + SZ_XE);
    __bf16* kb  = (__bf16*)(ws + 2 * SZ_XE);
    __bf16* vb  = (__bf16*)(ws + 3 * SZ_XE);
    __bf16* wqt = (__bf16*)(ws + 4 * SZ_XE);
    __bf16* wkt = (__bf16*)(ws + 4 * SZ_XE + SZ_W);
    __bf16* wvt = (__bf16*)(ws + 4 * SZ_XE + 2 * SZ_W);
    __bf16* wpb = (__bf16*)(ws + 4 * SZ_XE + 3 * SZ_W);
    __bf16* att = xb;  // alias: xb dead after QKV GEMMs (stream-ordered)

    // casts
    cast_f32_to_bf16<<<8192, 256, 0, stream>>>(x, xb, B_ * T_ * E_);
    cast_transpose_w<<<4096, 256, 0, stream>>>(Wq, wqt);
    cast_transpose_w<<<4096, 256, 0, stream>>>(Wk, wkt);
    cast_transpose_w<<<4096, 256, 0, stream>>>(Wv, wvt);
    cast_f32_to_bf16<<<1024, 256, 0, stream>>>(Wp, wpb, E_ * E_);

    // QKV projections: per z=(b*H+h): C[T][DH] = X_b[T][E] @ W_h[DH][E]^T
    long sA = (long)T_ * E_, sB = (long)DH_ * E_, sC = (long)T_ * DH_;
    gemm_bt<false><<<dim3(T_ / BM, 1, B_ * H_), 256, 0, stream>>>(
        xb, wqt, qb, nullptr, E_, DH_, sA, sB, sC, H_);
    gemm_bt<false><<<dim3(T_ / BM, 1, B_ * H_), 256, 0, stream>>>(
        xb, wkt, kb, nullptr, E_, DH_, sA, sB, sC, H_);
    gemm_bt<false><<<dim3(T_ / BM, 1, B_ * H_), 256, 0, stream>>>(
        xb, wvt, vb, nullptr, E_, DH_, sA, sB, sC, H_);

    // causal attention
    attn_kernel<<<dim3(T_ / 64, B_ * H_), 256, 0, stream>>>(qb, kb, vb, att);

    // output projection + bias (fp32 out)
    gemm_bt<true><<<dim3((B_ * T_) / BM, E_ / BN, 1), 256, 0, stream>>>(
        att, wpb, (float*)d_out, bp, E_, E_, 0, 0, 0, 1);
}